// Round 4
// baseline (937.085 us; speedup 1.0000x reference)
//
#include <hip/hip_runtime.h>
#include <hip/hip_bf16.h>
#include <cstdint>
#include <cstddef>

typedef __bf16 bf16x8 __attribute__((ext_vector_type(8)));
typedef float  f32x4  __attribute__((ext_vector_type(4)));

static constexpr int TOK  = 4096;            // B*S
static constexpr int H    = 2048;
static constexpr int E    = 8;
static constexpr int IDIM = 1024;
static constexpr int ISD  = 4096;
static constexpr int MAXT256 = 40;           // max 256-row tiles (32 + 8 remainders)
static constexpr int MAXT128 = 80;           // = 2 * MAXT256
static constexpr int MAXROWS = MAXT256 * 256;  // 10240 >= 2*TOK + 8*255 padded

// meta layout (ints):
//  [0]       bf16-input flag
//  [4..11]   cnt[e]       (token count per expert)
//  [12..19]  cursor[e]    (scatter cursors)
//  [20]      nTiles256    [21] nTiles128
//  [24..31]  segStart[e]  (256-padded prefix)   [32] total padded rows
//  [64..103]   tileExpert256[t]   [104..143] tileBase256[t]
//  [144..223]  tileExpert128[t]   [224..303] tileBase128[t]

// async global->LDS, 16B/lane; LDS dest = wave-uniform base + lane*16
__device__ __forceinline__ void gll16(const void* g, void* l) {
  __builtin_amdgcn_global_load_lds((const __attribute__((address_space(1))) void*)g,
                                   (__attribute__((address_space(3))) void*)l, 16, 0, 0);
}

__device__ __forceinline__ unsigned short f2bf(float f) {  // RNE fp32->bf16
  unsigned int u = __float_as_uint(f);
  u = (u + 0x7fffu + ((u >> 16) & 1u)) >> 16;
  return (unsigned short)u;
}

// ---- dtype detection + meta zeroing ----
__global__ __launch_bounds__(256) void detect_kernel(const unsigned int* __restrict__ x,
                                                     int* __restrict__ meta) {
  __shared__ int sh[256];
  const int tid = threadIdx.x;
  int c = 0;
  for (int i = tid; i < 1024; i += 256) {
    const unsigned int e = (x[i] >> 7) & 0xFFu;
    c += (e >= 100u && e <= 150u) ? 1 : 0;
  }
  sh[tid] = c;
  if (tid >= 4 && tid < 24) meta[tid] = 0;   // zero cnt[] and cursor[]
  __syncthreads();
  if (tid == 0) {
    int s = 0;
    for (int i = 0; i < 256; ++i) s += sh[i];
    meta[0] = (s > 512) ? 1 : 0;   // 1 => inputs bf16; 0 => fp32
  }
}

// ---- zero the fp32 accumulation target (out in fp32 mode, psum in bf16 mode) ----
__global__ __launch_bounds__(256) void zero_kernel(float* __restrict__ psum,
                                                   void* __restrict__ out,
                                                   const int* __restrict__ meta) {
  float* tgt = meta[0] ? psum : (float*)out;
  const float4 z = {0.f, 0.f, 0.f, 0.f};
  int i = blockIdx.x * 256 + threadIdx.x;
  const int stride = gridDim.x * 256;
  for (; i < (TOK * H) / 4; i += stride) ((float4*)tgt)[i] = z;
}

// ---- bf16-mode only: convert psum -> bf16 out (no-op in fp32 mode) ----
__global__ __launch_bounds__(256) void psum2bf_kernel(const float* __restrict__ psum,
                                                      unsigned short* __restrict__ out,
                                                      const int* __restrict__ meta) {
  if (!meta[0]) return;
  int i = blockIdx.x * 256 + threadIdx.x;
  const int stride = gridDim.x * 256;
  for (; i < (TOK * H) / 4; i += stride) {
    const float4 v = ((const float4*)psum)[i];
    ushort4 o;
    o.x = f2bf(v.x); o.y = f2bf(v.y); o.z = f2bf(v.z); o.w = f2bf(v.w);
    ((ushort4*)out)[i] = o;
  }
}

// ---- fused fp32 -> bf16 conversion for all 8 inputs (no-op when bf16) ----
__global__ __launch_bounds__(256) void convert_all_kernel(
    const float* __restrict__ s0, const float* __restrict__ s1,
    const float* __restrict__ s2, const float* __restrict__ s3,
    const float* __restrict__ s4, const float* __restrict__ s5,
    const float* __restrict__ s6, const float* __restrict__ s7,
    unsigned short* __restrict__ d0, unsigned short* __restrict__ d1,
    unsigned short* __restrict__ d2, unsigned short* __restrict__ d3,
    unsigned short* __restrict__ d4, unsigned short* __restrict__ d5,
    unsigned short* __restrict__ d6, unsigned short* __restrict__ d7,
    const int* __restrict__ flag)
{
  if (*flag) return;
  const int stride = gridDim.x * 256;
  const int base = blockIdx.x * 256 + threadIdx.x;
  auto go = [&](const float* s, unsigned short* d, int n4) {
    for (int i = base; i < n4; i += stride) {
      const float4 v = ((const float4*)s)[i];
      ushort4 o;
      o.x = f2bf(v.x); o.y = f2bf(v.y); o.z = f2bf(v.z); o.w = f2bf(v.w);
      ((ushort4*)d)[i] = o;
    }
  };
  go(s0, d0, (TOK * H) / 4);
  go(s1, d1, (E * H) / 4);
  go(s2, d2, (E * IDIM * H) / 4);
  go(s3, d3, (E * IDIM * H) / 4);
  go(s4, d4, (E * H * IDIM) / 4);
  go(s5, d5, (ISD * H) / 4);
  go(s6, d6, (ISD * H) / 4);
  go(s7, d7, (ISD * H) / 4);
}

// ---- router: one WAVE per token; fp32 logits, top-2, sigmoid, counting ----
__global__ __launch_bounds__(256) void router_kernel(
    const void* __restrict__ x_, const void* __restrict__ rw_,
    void* __restrict__ out, float* __restrict__ scale,
    int* __restrict__ meta, int* __restrict__ topk)
{
  const int bfmode = meta[0];
  const int t = blockIdx.x * 4 + (threadIdx.x >> 6);
  const int l = threadIdx.x & 63;
  const int off = l * 32;

  float xs[32];
  if (bfmode) {
    const unsigned short* xr = (const unsigned short*)x_ + (size_t)t * H + off;
#pragma unroll
    for (int j = 0; j < 4; ++j) {
      bf16x8 v = *(const bf16x8*)(xr + j * 8);
#pragma unroll
      for (int k = 0; k < 8; ++k) xs[j * 8 + k] = (float)v[k];
    }
  } else {
    const float* xr = (const float*)x_ + (size_t)t * H + off;
#pragma unroll
    for (int j = 0; j < 8; ++j) {
      const float4 v = *(const float4*)(xr + j * 4);
      xs[j * 4] = v.x; xs[j * 4 + 1] = v.y; xs[j * 4 + 2] = v.z; xs[j * 4 + 3] = v.w;
    }
  }

  float p[E];
#pragma unroll
  for (int e = 0; e < E; ++e) {
    float s = 0.f;
    if (bfmode) {
      const unsigned short* wr = (const unsigned short*)rw_ + (size_t)e * H + off;
#pragma unroll
      for (int j = 0; j < 4; ++j) {
        bf16x8 v = *(const bf16x8*)(wr + j * 8);
#pragma unroll
        for (int k = 0; k < 8; ++k) s = fmaf(xs[j * 8 + k], (float)v[k], s);
      }
    } else {
      const float* wr = (const float*)rw_ + (size_t)e * H + off;
#pragma unroll
      for (int j = 0; j < 8; ++j) {
        const float4 v = *(const float4*)(wr + j * 4);
        s = fmaf(xs[j * 4], v.x, s);     s = fmaf(xs[j * 4 + 1], v.y, s);
        s = fmaf(xs[j * 4 + 2], v.z, s); s = fmaf(xs[j * 4 + 3], v.w, s);
      }
    }
    p[e] = s;
  }
#pragma unroll
  for (int e = 0; e < E; ++e)
#pragma unroll
    for (int o = 32; o > 0; o >>= 1) p[e] += __shfl_down(p[e], o);

  if (l == 0) {
    int i0 = 0; float v0 = p[0];
#pragma unroll
    for (int e = 1; e < E; ++e) if (p[e] > v0) { v0 = p[e]; i0 = e; }
    int i1 = -1; float v1 = 0.f; bool init = false;
#pragma unroll
    for (int e = 0; e < E; ++e) {
      if (e == i0) continue;
      if (!init || p[e] > v1) { v1 = p[e]; i1 = e; init = true; }
    }
    const float s0 = 1.f / (1.f + expf(-v0));
    const float s1 = 1.f / (1.f + expf(-v1));
    topk[2 * t + 0] = i0;
    topk[2 * t + 1] = i1;
    atomicAdd(&meta[4 + i0], 1);
    atomicAdd(&meta[4 + i1], 1);
    const size_t oi = (size_t)TOK * H + (size_t)t * E;
#pragma unroll
    for (int e = 0; e < E; ++e) {
      if (bfmode) ((unsigned short*)out)[oi + e] = f2bf(p[e]);
      else        ((float*)out)[oi + e] = p[e];
      scale[(size_t)t * E + e] = (e == i0) ? s0 : ((e == i1) ? s1 : 0.f);
    }
  }
}

// ---- tiny scan: 256-padded segment starts + both tile maps; list = -1 sentinel ----
__global__ __launch_bounds__(256) void scan_kernel(int* __restrict__ meta,
                                                   int* __restrict__ list) {
  const int tid = threadIdx.x;
  if (tid == 0) {
    int s = 0, n256 = 0, n128 = 0;
    for (int e = 0; e < E; ++e) {
      meta[24 + e] = s;
      const int cnt = meta[4 + e];
      const int tiles = (cnt + 255) >> 8;
      for (int i = 0; i < tiles; ++i) {
        meta[64 + n256]  = e;
        meta[104 + n256] = s + i * 256;
        ++n256;
        meta[144 + n128] = e; meta[224 + n128] = s + i * 256;       ++n128;
        meta[144 + n128] = e; meta[224 + n128] = s + i * 256 + 128; ++n128;
      }
      s += tiles << 8;
    }
    meta[32] = s;      // total padded rows
    meta[20] = n256;   // 256-row tiles
    meta[21] = n128;   // 128-row tiles
  }
  for (int i = tid; i < MAXROWS; i += 256) list[i] = -1;  // pad sentinel
}

// ---- scatter token ids into per-expert padded lists ----
__global__ __launch_bounds__(256) void scatter_kernel(int* __restrict__ meta,
                                                      const int* __restrict__ topk,
                                                      int* __restrict__ list) {
  const int t = blockIdx.x * 256 + threadIdx.x;
  if (t >= TOK) return;
#pragma unroll
  for (int k = 0; k < 2; ++k) {
    const int e = topk[2 * t + k];
    const int p = atomicAdd(&meta[12 + e], 1);
    list[meta[24 + e] + p] = t;
  }
}

// ============================================================================
// 8-phase 256-geometry pipeline (T2+T3+T4+T5) — shared by all 8-phase kernels.
// Tile: 256 A-rows x 256 B-rows (B = [gate|up] for gateup, plain rows for down).
// 8 waves (wm 0..1 x wn 0..3), strip-interleaved.
// vmcnt(4) at P4/P8 (2 half-tile stages in flight); vmcnt(0) only in peel.
// K per invocation = 2048 (KT=32).
// ============================================================================
#define GU_BAR_   __builtin_amdgcn_s_barrier()
#define GU_LGKM0_ { asm volatile("s_waitcnt lgkmcnt(0)" ::: "memory"); \
                    __builtin_amdgcn_sched_barrier(0); }
#define GU_VM4_   asm volatile("s_waitcnt vmcnt(4)" ::: "memory")
#define GU_VM0_   asm volatile("s_waitcnt vmcnt(0)" ::: "memory")

#define LDA_(p, mh) { _Pragma("unroll") for (int q2 = 0; q2 < 4; ++q2) { \
  _Pragma("unroll") for (int ks = 0; ks < 2; ++ks) { \
    const int row_ = 32 * (4 * (mh) + q2) + 16 * wm + lm; \
    a[q2][ks] = *(const bf16x8*)&ldsA[(p) * 16384 + row_ * 64 + \
                                      (((ks * 4 + quad) ^ (lm & 7)) * 8)]; } } }

#define LDB_(p, nh) { _Pragma("unroll") for (int nt2 = 0; nt2 < 2; ++nt2) { \
  _Pragma("unroll") for (int ks = 0; ks < 2; ++ks) { \
    const int row_ = 16 * (wn + 4 * (2 * (nh) + nt2)) + lm; \
    bb[nh][nt2][ks] = *(const bf16x8*)&ldsB[(p) * 16384 + row_ * 64 + \
                                            (((ks * 4 + quad) ^ (lm & 7)) * 8)]; } } }

#define MFMA_(mh, nh) { __builtin_amdgcn_s_setprio(1); \
  _Pragma("unroll") for (int q2 = 0; q2 < 4; ++q2) \
  _Pragma("unroll") for (int nt2 = 0; nt2 < 2; ++nt2) \
  _Pragma("unroll") for (int ks = 0; ks < 2; ++ks) \
    acc[4 * (mh) + q2][2 * (nh) + nt2] = __builtin_amdgcn_mfma_f32_16x16x32_bf16( \
      a[q2][ks], bb[nh][nt2][ks], acc[4 * (mh) + q2][2 * (nh) + nt2], 0, 0, 0); \
  __builtin_amdgcn_s_setprio(0); }

// K-loop body (KT = 32 tiles of 64); STA/STB are lambdas (kt, half).
#define GU_PIPELINE_(STA, STB) \
  STA(0, 0); STB(0, 0); STB(0, 1); STA(0, 1); \
  STB(1, 1); STA(1, 1); \
  GU_VM4_; GU_BAR_; \
  for (int i = 0; i < (H / 128) - 1; ++i) { \
    const int t0 = 2 * i, t1 = 2 * i + 1; \
    LDA_(0, 0); LDB_(0, 0); STA(t1, 0); \
    GU_BAR_; GU_LGKM0_; MFMA_(0, 0); GU_BAR_; \
    LDB_(0, 1); STB(t1, 0); \
    GU_BAR_; GU_LGKM0_; MFMA_(0, 1); GU_BAR_; \
    LDA_(0, 1); STA(t0 + 2, 0); \
    GU_BAR_; GU_LGKM0_; MFMA_(1, 1); GU_BAR_; \
    STB(t0 + 2, 0); GU_VM4_; \
    GU_BAR_; GU_LGKM0_; MFMA_(1, 0); GU_BAR_; \
    LDA_(1, 0); LDB_(1, 0); STB(t0 + 2, 1); \
    GU_BAR_; GU_LGKM0_; MFMA_(0, 0); GU_BAR_; \
    LDB_(1, 1); STA(t0 + 2, 1); \
    GU_BAR_; GU_LGKM0_; MFMA_(0, 1); GU_BAR_; \
    LDA_(1, 1); STB(t1 + 2, 1); \
    GU_BAR_; GU_LGKM0_; MFMA_(1, 1); GU_BAR_; \
    STA(t1 + 2, 1); GU_VM4_; \
    GU_BAR_; GU_LGKM0_; MFMA_(1, 0); GU_BAR_; \
  } \
  { \
    const int t1 = H / 64 - 1; \
    LDA_(0, 0); LDB_(0, 0); STA(t1, 0); \
    GU_BAR_; GU_LGKM0_; MFMA_(0, 0); GU_BAR_; \
    LDB_(0, 1); STB(t1, 0); \
    GU_BAR_; GU_LGKM0_; MFMA_(0, 1); GU_BAR_; \
    LDA_(0, 1); \
    GU_BAR_; GU_LGKM0_; MFMA_(1, 1); GU_BAR_; \
    GU_VM0_; \
    GU_BAR_; GU_LGKM0_; MFMA_(1, 0); GU_BAR_; \
    LDA_(1, 0); LDB_(1, 0); \
    GU_BAR_; GU_LGKM0_; MFMA_(0, 0); GU_BAR_; \
    LDB_(1, 1); \
    GU_BAR_; GU_LGKM0_; MFMA_(0, 1); GU_BAR_; \
    LDA_(1, 1); \
    GU_BAR_; GU_LGKM0_; MFMA_(1, 1); GU_BAR_; \
    MFMA_(1, 0); \
  }

__global__ __launch_bounds__(512, 2) void gateup_shared_kernel(
    const void* __restrict__ xo_,  const unsigned short* __restrict__ cx,
    const void* __restrict__ sgo_, const unsigned short* __restrict__ csgw,
    const void* __restrict__ suo_, const unsigned short* __restrict__ csuw,
    unsigned short* __restrict__ hmid_sh, const int* __restrict__ meta)
{
  extern __shared__ unsigned short lds[];
  unsigned short* ldsA = lds;             // [2][256*64] bf16 (64 KiB)
  unsigned short* ldsB = lds + 32768;     // [2][256*64] bf16 (64 KiB)

  const int bfmode = meta[0];
  const unsigned short* x  = bfmode ? (const unsigned short*)xo_  : cx;
  const unsigned short* gw = bfmode ? (const unsigned short*)sgo_ : csgw;
  const unsigned short* uw = bfmode ? (const unsigned short*)suo_ : csuw;

  const int tid = threadIdx.x;
  const int l = tid & 63, w = tid >> 6;
  const int wm = w >> 2, wn = w & 3;
  const int quad = l >> 4, lm = l & 15;
  const int m0 = blockIdx.x * 256;
  const int jb = blockIdx.y * 128;

  const unsigned short* gB = gw + (size_t)jb * H;
  const unsigned short* uB = uw + (size_t)jb * H;

  const int sr0 = tid >> 3,         sc0 = tid & 7;
  const int sr1 = (tid + 512) >> 3, sc1 = (tid + 512) & 7;
  const int scc0 = sc0 ^ (sr0 & 7), scc1 = sc1 ^ (sr1 & 7);
  const int sd0 = tid * 8, sd1 = (tid + 512) * 8;

  auto stA = [&](int kt, int half) {
    unsigned short* d = ldsA + (kt & 1) * 16384 + half * 8192;
    const unsigned short* s = x + (size_t)(m0 + half * 128) * H + kt * 64;
    gll16(s + (size_t)sr0 * H + scc0 * 8, d + sd0);
    gll16(s + (size_t)sr1 * H + scc1 * 8, d + sd1);
  };
  auto stB = [&](int kt, int half) {
    unsigned short* d = ldsB + (kt & 1) * 16384 + half * 8192;
    const unsigned short* s = (half ? uB : gB) + kt * 64;
    gll16(s + (size_t)sr0 * H + scc0 * 8, d + sd0);
    gll16(s + (size_t)sr1 * H + scc1 * 8, d + sd1);
  };

  f32x4 acc[8][4] = {};
  bf16x8 a[4][2];
  bf16x8 bb[2][2][2];

  GU_PIPELINE_(stA, stB);

  // epilogue: gate (cg 0,1) pairs with up (cg 2,3) in-wave, in-register
#pragma unroll
  for (int mt = 0; mt < 8; ++mt) {
    const int trow = m0 + 32 * mt + 16 * wm + quad * 4;
#pragma unroll
    for (int ntp = 0; ntp < 2; ++ntp) {
      const int col = jb + wn * 16 + ntp * 64 + lm;
#pragma unroll
      for (int rr = 0; rr < 4; ++rr) {
        const float g = acc[mt][ntp][rr];
        const float u = acc[mt][ntp + 2][rr];
        const float hm = (g / (1.f + expf(-g))) * u;
        hmid_sh[(size_t)(trow + rr) * ISD + col] = f2bf(hm);
      }
    }
  }
}

// ---- routed gate+up, 8-phase 256-geometry with gathered A rows ----
// grid: x = 256-row tile (MAXT256, early-exit), y = IDIM/128 = 8
__global__ __launch_bounds__(512, 2) void gateup_routed_kernel(
    const void* __restrict__ xo_,  const unsigned short* __restrict__ cx,
    const void* __restrict__ gwo_, const unsigned short* __restrict__ cgw,
    const void* __restrict__ uwo_, const unsigned short* __restrict__ cuw,
    const float* __restrict__ scale, const int* __restrict__ list,
    unsigned short* __restrict__ hmid_r, const int* __restrict__ meta)
{
  if ((int)blockIdx.x >= meta[20]) return;
  extern __shared__ unsigned short lds[];
  unsigned short* ldsA = lds;
  unsigned short* ldsB = lds + 32768;

  const int bfmode = meta[0];
  const unsigned short* x      = bfmode ? (const unsigned short*)xo_  : cx;
  const unsigned short* gate_w = bfmode ? (const unsigned short*)gwo_ : cgw;
  const unsigned short* up_w   = bfmode ? (const unsigned short*)uwo_ : cuw;

  const int tid = threadIdx.x;
  const int l = tid & 63, w = tid >> 6;
  const int wm = w >> 2, wn = w & 3;
  const int quad = l >> 4, lm = l & 15;
  const int e    = meta[64 + blockIdx.x];
  const int base = meta[104 + blockIdx.x];
  const int jb   = blockIdx.y * 128;

  const unsigned short* gB = gate_w + ((size_t)e * IDIM + jb) * H;
  const unsigned short* uB = up_w   + ((size_t)e * IDIM + jb) * H;

  const int sr0 = tid >> 3,         sc0 = tid & 7;
  const int sr1 = (tid + 512) >> 3, sc1 = (tid + 512) & 7;
  const int scc0 = sc0 ^ (sr0 & 7), scc1 = sc1 ^ (sr1 & 7);
  const int sd0 = tid * 8, sd1 = (tid + 512) * 8;

  // gathered token ids (clamped; -1 sentinel rows load token 0, scaled to 0)
  int tokh[2][2];
#pragma unroll
  for (int h = 0; h < 2; ++h) {
    const int ta = list[base + h * 128 + sr0];
    const int tb = list[base + h * 128 + sr1];
    tokh[h][0] = ta < 0 ? 0 : ta;
    tokh[h][1] = tb < 0 ? 0 : tb;
  }

  auto stA = [&](int kt, int half) {
    unsigned short* d = ldsA + (kt & 1) * 16384 + half * 8192;
    gll16(x + (size_t)tokh[half][0] * H + kt * 64 + scc0 * 8, d + sd0);
    gll16(x + (size_t)tokh[half][1] * H + kt * 64 + scc1 * 8, d + sd1);
  };
  auto stB = [&](int kt, int half) {
    unsigned short* d = ldsB + (kt & 1) * 16384 + half * 8192;
    const unsigned short* s = (half ? uB : gB) + kt * 64;
    gll16(s + (size_t)sr0 * H + scc0 * 8, d + sd0);
    gll16(s + (size_t)sr1 * H + scc1 * 8, d + sd1);
  };

  f32x4 acc[8][4] = {};
  bf16x8 a[4][2];
  bf16x8 bb[2][2][2];

  GU_PIPELINE_(stA, stB);

  // epilogue: scale expert inputs (0 for pad rows), silu(g*s)*(u*s)
#pragma unroll
  for (int mt = 0; mt < 8; ++mt) {
    const int rloc = 32 * mt + 16 * wm + quad * 4;
#pragma unroll
    for (int rr = 0; rr < 4; ++rr) {
      const int gpos = base + rloc + rr;
      const int token = list[gpos];
      const float s = token < 0 ? 0.f : scale[(size_t)token * E + e];
#pragma unroll
      for (int ntp = 0; ntp < 2; ++ntp) {
        const int col = jb + wn * 16 + ntp * 64 + lm;
        const float g = acc[mt][ntp][rr] * s;
        const float u = acc[mt][ntp + 2][rr] * s;
        const float hm = (g / (1.f + expf(-g))) * u;
        hmid_r[(size_t)gpos * IDIM + col] = f2bf(hm);
      }
    }
  }
}

// ---- shared down, 8-phase, K-split z=2, atomicAdd into fp32 target ----
// grid: x = out-col-tile (H/256 = 8), y = token-tile (TOK/256 = 16), z = K half
__global__ __launch_bounds__(512, 2) void down_shared_kernel(
    const unsigned short* __restrict__ hmid_sh,
    const void* __restrict__ sdwo_, const unsigned short* __restrict__ csdw,
    float* __restrict__ psum, void* __restrict__ out, const int* __restrict__ meta)
{
  extern __shared__ unsigned short lds[];
  unsigned short* ldsA = lds;
  unsigned short* ldsB = lds + 32768;

  const int bfmode = meta[0];
  const unsigned short* sdw = bfmode ? (const unsigned short*)sdwo_ : csdw;
  float* tgt = bfmode ? psum : (float*)out;

  const int tid = threadIdx.x;
  const int l = tid & 63, w = tid >> 6;
  const int wm = w >> 2, wn = w & 3;
  const int quad = l >> 4, lm = l & 15;
  const int m0 = blockIdx.y * 256;
  const int n0 = blockIdx.x * 256;
  const int kbase = blockIdx.z * (ISD / 2);   // 0 or 2048 (KT=32 each)

  const int sr0 = tid >> 3,         sc0 = tid & 7;
  const int sr1 = (tid + 512) >> 3, sc1 = (tid + 512) & 7;
  const int scc0 = sc0 ^ (sr0 & 7), scc1 = sc1 ^ (sr1 & 7);
  const int sd0 = tid * 8, sd1 = (tid + 512) * 8;

  auto stA = [&](int kt, int half) {
    unsigned short* d = ldsA + (kt & 1) * 16384 + half * 8192;
    const unsigned short* s = hmid_sh + (size_t)(m0 + half * 128) * ISD + kbase + kt * 64;
    gll16(s + (size_t)sr0 * ISD + scc0 * 8, d + sd0);
    gll16(s + (size_t)sr1 * ISD + scc1 * 8, d + sd1);
  };
  auto stB = [&](int kt, int half) {
    unsigned short* d = ldsB + (kt & 1) * 16384 + half * 8192;
    const unsigned short* s = sdw + (size_t)(n0 + half * 128) * ISD + kbase + kt * 64;
    gll16(s + (size_t)sr0 * ISD + scc0 * 8, d + sd0);
    gll16(s + (size_t)sr1 * ISD + scc1 * 8, d + sd1);
  };

  f32x4 acc[8][4] = {};
  bf16x8 a[4][2];
  bf16x8 bb[2][2][2];

  GU_PIPELINE_(stA, stB);

#pragma unroll
  for (int mt = 0; mt < 8; ++mt) {
#pragma unroll
    for (int rr = 0; rr < 4; ++rr) {
      const int t = m0 + 32 * mt + 16 * wm + quad * 4 + rr;
#pragma unroll
      for (int cg = 0; cg < 4; ++cg) {
        const int n = n0 + 16 * (wn + 4 * cg) + lm;
        atomicAdd(&tgt[(size_t)t * H + n], acc[mt][cg][rr]);
      }
    }
  }
}

// ---- routed down: atomicAdd per-token into fp32 target (no dbuf) ----
// grid: x = out-col-tile (H/128 = 16, fastest), y = 128-row tile (early-exit)
__global__ __launch_bounds__(256) void down_routed_kernel(
    const unsigned short* __restrict__ hmid_r,
    const void* __restrict__ dwo_, const unsigned short* __restrict__ cdw,
    float* __restrict__ psum, void* __restrict__ out,
    const int* __restrict__ list, const int* __restrict__ meta)
{
  if ((int)blockIdx.y >= meta[21]) return;
  const int bfmode = meta[0];
  const unsigned short* down_w = bfmode ? (const unsigned short*)dwo_ : cdw;
  float* tgt = bfmode ? psum : (float*)out;

  __shared__ __attribute__((aligned(16))) unsigned short As[128 * 64];
  __shared__ __attribute__((aligned(16))) unsigned short Bs[128 * 64];

  const int tid = threadIdx.x;
  const int l = tid & 63, w = tid >> 6;
  const int e    = meta[144 + blockIdx.y];
  const int base = meta[224 + blockIdx.y];
  const int n0 = blockIdx.x * 128;

  const unsigned short* Bbase = down_w + ((size_t)e * H + n0) * IDIM;

  f32x4 acc[4][4] = {};
  const int wm = (w >> 1) * 64;
  const int wn = (w & 1) * 64;
  const int quad = l >> 4, lm = l & 15;

  for (int k0 = 0; k0 < IDIM; k0 += 64) {
#pragma unroll
    for (int j = 0; j < 4; ++j) {
      const int g = j * 256 + tid;
      const int r = g >> 3, c = g & 7;
      const int cc = c ^ (r & 7);
      gll16(hmid_r + (size_t)(base + r) * IDIM + k0 + cc * 8, &As[g * 8]);
    }
#pragma unroll
    for (int j = 0; j < 4; ++j) {
      const int g = j * 256 + tid;
      const int r = g >> 3, c = g & 7;
      const int cc = c ^ (r & 7);
      gll16(Bbase + (size_t)r * IDIM + k0 + cc * 8, &Bs[g * 8]);
    }
    __syncthreads();
#pragma unroll
    for (int ks = 0; ks < 64; ks += 32) {
      const int kc  = (ks >> 3) + quad;
      const int csw = (kc ^ (lm & 7)) * 8;
      bf16x8 a[4], b[4];
#pragma unroll
      for (int mt = 0; mt < 4; ++mt)
        a[mt] = *(const bf16x8*)&As[(wm + mt * 16 + lm) * 64 + csw];
#pragma unroll
      for (int nt = 0; nt < 4; ++nt)
        b[nt] = *(const bf16x8*)&Bs[(wn + nt * 16 + lm) * 64 + csw];
#pragma unroll
      for (int mt = 0; mt < 4; ++mt)
#pragma unroll
        for (int nt = 0; nt < 4; ++nt)
          acc[mt][nt] = __builtin_amdgcn_mfma_f32_16x16x32_bf16(a[mt], b[nt], acc[mt][nt], 0, 0, 0);
    }
    __syncthreads();
  }

#pragma unroll
  for (int mt = 0; mt < 4; ++mt)
#pragma unroll
    for (int r = 0; r < 4; ++r) {
      const int row = wm + mt * 16 + quad * 4 + r;
      const int token = list[base + row];
      if (token < 0) continue;
#pragma unroll
      for (int nt = 0; nt < 4; ++nt) {
        const int n = n0 + wn + nt * 16 + lm;
        atomicAdd(&tgt[(size_t)token * H + n], acc[mt][nt][r]);
      }
    }
}

extern "C" void kernel_launch(void* const* d_in, const int* in_sizes, int n_in,
                              void* d_out, int out_size, void* d_ws, size_t ws_size,
                              hipStream_t stream) {
  const void* x   = d_in[0];
  const void* rw  = d_in[1];
  const void* gw  = d_in[2];
  const void* uw  = d_in[3];
  const void* dw  = d_in[4];
  const void* sgw = d_in[5];
  const void* suw = d_in[6];
  const void* sdw = d_in[7];

  char* wsb = (char*)d_ws;
  int*   meta   = (int*)wsb;                                  // 2048 B
  float* scale  = (float*)(wsb + 2048);                       // TOK*E fp32 (128 KiB)
  int*   topk   = (int*)(wsb + 2048 + (size_t)TOK * E * 4);   // TOK*2 (32 KiB)
  int*   list   = topk + (size_t)TOK * 2;                     // MAXROWS (40 KiB)
  unsigned short* hmid_sh = (unsigned short*)(wsb + 262144);  // [TOK,ISD] bf16 (32 MiB)
  unsigned short* hmid_r  = hmid_sh + (size_t)TOK * ISD;      // [MAXROWS,IDIM] bf16 (20 MiB)
  unsigned short* cx   = hmid_r + (size_t)MAXROWS * IDIM;
  unsigned short* crw  = cx  + (size_t)TOK * H;
  unsigned short* cgw  = crw + (size_t)E * H;
  unsigned short* cuw  = cgw + (size_t)E * IDIM * H;
  unsigned short* cdw  = cuw + (size_t)E * IDIM * H;
  unsigned short* csgw = cdw + (size_t)E * H * IDIM;
  unsigned short* csuw = csgw + (size_t)ISD * H;
  unsigned short* csdw = csuw + (size_t)ISD * H;
  // psum fp32 [TOK,H] = 33.5 MB aliases cx (bf16 mode only: cx unused there;
  // fp32 mode writes go directly to d_out and psum is never touched).
  float* psum = (float*)cx;

  static int attr_set = 0;
  if (!attr_set) {
    hipFuncSetAttribute(reinterpret_cast<const void*>(gateup_shared_kernel),
                        hipFuncAttributeMaxDynamicSharedMemorySize, 131072);
    hipFuncSetAttribute(reinterpret_cast<const void*>(gateup_routed_kernel),
                        hipFuncAttributeMaxDynamicSharedMemorySize, 131072);
    hipFuncSetAttribute(reinterpret_cast<const void*>(down_shared_kernel),
                        hipFuncAttributeMaxDynamicSharedMemorySize, 131072);
    attr_set = 1;
  }

  detect_kernel<<<1, 256, 0, stream>>>((const unsigned int*)x, meta);
  zero_kernel<<<1024, 256, 0, stream>>>(psum, d_out, meta);

  convert_all_kernel<<<2048, 256, 0, stream>>>(
      (const float*)x, (const float*)rw, (const float*)gw, (const float*)uw,
      (const float*)dw, (const float*)sgw, (const float*)suw, (const float*)sdw,
      cx, crw, cgw, cuw, cdw, csgw, csuw, csdw, meta);

  router_kernel<<<TOK / 4, 256, 0, stream>>>(x, rw, d_out, scale, meta, topk);
  scan_kernel<<<1, 256, 0, stream>>>(meta, list);
  scatter_kernel<<<TOK / 256, 256, 0, stream>>>(meta, topk, list);

  dim3 g1(TOK / 256, ISD / 128);      // 16 x 32
  gateup_shared_kernel<<<g1, 512, 131072, stream>>>(x, cx, sgw, csgw, suw, csuw,
                                                    hmid_sh, meta);

  dim3 g2(MAXT256, IDIM / 128);       // 40 x 8 (early-exit past nTiles256)
  gateup_routed_kernel<<<g2, 512, 131072, stream>>>(x, cx, gw, cgw, uw, cuw,
                                                    scale, list, hmid_r, meta);

  dim3 g3(H / 256, TOK / 256, 2);     // 8 x 16 x 2 = 256 blocks, exactly 1 round
  down_shared_kernel<<<g3, 512, 131072, stream>>>(hmid_sh, sdw, csdw, psum, d_out, meta);

  dim3 g4(H / 128, MAXT128);          // 16 x 80 (early-exit past nTiles128)
  down_routed_kernel<<<g4, 256, 0, stream>>>(hmid_r, dw, cdw, psum, d_out, list, meta);

  psum2bf_kernel<<<1024, 256, 0, stream>>>(psum, (unsigned short*)d_out, meta);
}